// Round 1
// baseline (23.150 us; speedup 1.0000x reference)
//
#include <hip/hip_runtime.h>

#define D_IN  48
#define H_IN  64
#define W_IN  128
#define D_OUT 193
#define H_OUT 256
#define W_OUT 512

// One thread per output pixel (b,h,w). Fuses trilinear upsample + softmax(-vol)
// + expected-disparity reduction. c[48] kept in registers; d-loop fully
// unrolled so c[] indices are compile-time constants (no scratch).
__global__ __launch_bounds__(256) void disp_kernel(const float* __restrict__ x,
                                                   float* __restrict__ out) {
    int tid = blockIdx.x * blockDim.x + threadIdx.x;
    int w = tid & (W_OUT - 1);
    int h = (tid >> 9) & (H_OUT - 1);
    int b = tid >> 17;

    // --- h interpolation (half-pixel, clamped) ---
    float hf = (h + 0.5f) * 0.25f - 0.5f;
    float hfl = floorf(hf);
    int h0 = (int)hfl;
    float fh = hf - hfl;
    if (h0 < 0) { h0 = 0; fh = 0.f; }
    if (h0 >= H_IN - 1) { h0 = H_IN - 1; fh = 0.f; }
    int h1 = (h0 + 1 < H_IN) ? h0 + 1 : H_IN - 1;

    // --- w interpolation ---
    float wf = (w + 0.5f) * 0.25f - 0.5f;
    float wfl = floorf(wf);
    int w0 = (int)wfl;
    float fw = wf - wfl;
    if (w0 < 0) { w0 = 0; fw = 0.f; }
    if (w0 >= W_IN - 1) { w0 = W_IN - 1; fw = 0.f; }
    int w1 = (w0 + 1 < W_IN) ? w0 + 1 : W_IN - 1;

    float w00 = (1.f - fh) * (1.f - fw);
    float w01 = (1.f - fh) * fw;
    float w10 = fh * (1.f - fw);
    float w11 = fh * fw;

    const float* xb = x + (size_t)b * (D_IN * H_IN * W_IN);
    int base00 = h0 * W_IN + w0;
    int base01 = h0 * W_IN + w1;
    int base10 = h1 * W_IN + w0;
    int base11 = h1 * W_IN + w1;

    // --- bilinear column c[k], track min for softmax bound ---
    float c[D_IN];
    float cmin = 1e30f;
    #pragma unroll
    for (int k = 0; k < D_IN; ++k) {
        int off = k * (H_IN * W_IN);
        float a  = xb[off + base00];
        float bb = xb[off + base01];
        float cc = xb[off + base10];
        float dd = xb[off + base11];
        float v = w00 * a + w01 * bb + w10 * cc + w11 * dd;
        c[k] = v;
        cmin = fminf(cmin, v);
    }

    // --- d loop: vol[d] = lerp(c[k0], c[k1], fd); softmax(-vol); E[d] ---
    // df(d) = (d+0.5)*(48/193) - 0.5 = (96d - 145)/386  (exact integer form)
    float sum = 0.f, dsum = 0.f;
    #pragma unroll
    for (int d = 0; d < D_OUT; ++d) {
        int num = 96 * d - 145;
        int k0 = (num >= 0) ? (num / 386) : -1;
        float fd = (float)(num - 386 * k0) * (1.0f / 386.0f);
        if (k0 < 0) { k0 = 0; fd = 0.f; }
        if (k0 >= D_IN - 1) { k0 = D_IN - 1; fd = 0.f; }
        int k1 = (k0 + 1 < D_IN) ? k0 + 1 : D_IN - 1;
        float vol = c[k0] + fd * (c[k1] - c[k0]);
        float e = __expf(cmin - vol);   // arg <= 0, no overflow
        sum  += e;
        dsum += (float)d * e;
    }

    out[tid] = dsum / sum;
}

extern "C" void kernel_launch(void* const* d_in, const int* in_sizes, int n_in,
                              void* d_out, int out_size, void* d_ws, size_t ws_size,
                              hipStream_t stream) {
    const float* x = (const float*)d_in[0];
    float* out = (float*)d_out;
    int total = 2 * H_OUT * W_OUT;           // 262144
    disp_kernel<<<total / 256, 256, 0, stream>>>(x, out);
}

// Round 2
// 20.368 us; speedup vs baseline: 1.1366x; 1.1366x over previous
//
#include <hip/hip_runtime.h>

#define D_IN  48
#define H_IN  64
#define W_IN  128
#define D_OUT 193
#define H_OUT 256
#define W_OUT 512

// One thread per output pixel (b,h,w). Fuses trilinear upsample + softmax(-vol)
// + expected-disparity reduction.
//
// Key identity: softmax arg (cmin - vol[d]) * log2(e) is an affine map of
// vol, and lerp commutes with affine maps -> precompute g[k] =
// (cmin - c[k])*log2e in place, then per d: arg = g[k0] + fd*(g[k1]-g[k0]),
// e = exp2(arg) via the native v_exp_f32. The segment delta g[k1]-g[k0] is
// CSE'd across the ~4 unrolled d's sharing k0.
__global__ __launch_bounds__(256) void disp_kernel(const float* __restrict__ x,
                                                   float* __restrict__ out) {
    int tid = blockIdx.x * blockDim.x + threadIdx.x;
    int w = tid & (W_OUT - 1);
    int h = (tid >> 9) & (H_OUT - 1);
    int b = tid >> 17;                      // block-uniform -> SGPR base

    // --- h interpolation (half-pixel, clamped) ---
    float hf = (h + 0.5f) * 0.25f - 0.5f;
    float hfl = floorf(hf);
    int h0 = (int)hfl;
    float fh = hf - hfl;
    if (h0 < 0) { h0 = 0; fh = 0.f; }
    if (h0 >= H_IN - 1) { h0 = H_IN - 1; fh = 0.f; }
    int h1 = (h0 + 1 < H_IN) ? h0 + 1 : H_IN - 1;

    // --- w interpolation ---
    float wf = (w + 0.5f) * 0.25f - 0.5f;
    float wfl = floorf(wf);
    int w0 = (int)wfl;
    float fw = wf - wfl;
    if (w0 < 0) { w0 = 0; fw = 0.f; }
    if (w0 >= W_IN - 1) { w0 = W_IN - 1; fw = 0.f; }
    int w1 = (w0 + 1 < W_IN) ? w0 + 1 : W_IN - 1;

    float w00 = (1.f - fh) * (1.f - fw);
    float w01 = (1.f - fh) * fw;
    float w10 = fh * (1.f - fw);
    float w11 = fh * fw;

    const float* xb = x + (size_t)b * (D_IN * H_IN * W_IN);
    int base00 = h0 * W_IN + w0;
    int base01 = h0 * W_IN + w1;
    int base10 = h1 * W_IN + w0;
    int base11 = h1 * W_IN + w1;

    // --- bilinear column c[k], track min (softmax upper-bound on -vol) ---
    float c[D_IN];
    float cmin = 1e30f;
    #pragma unroll
    for (int k = 0; k < D_IN; ++k) {
        int off = k * (H_IN * W_IN);
        float a  = xb[off + base00];
        float bb = xb[off + base01];
        float cc = xb[off + base10];
        float dd = xb[off + base11];
        float v = w00 * a + w01 * bb + w10 * cc + w11 * dd;
        c[k] = v;
        cmin = fminf(cmin, v);
    }

    // --- transform in place: g[k] = (cmin - c[k]) * log2e  (<= 0) ---
    const float L2E = 1.4426950408889634f;
    float gbase = cmin * L2E;
    #pragma unroll
    for (int k = 0; k < D_IN; ++k) {
        c[k] = fmaf(c[k], -L2E, gbase);
    }

    // --- d loop: arg = lerp(g[k0], g[k1], fd); e = 2^arg; accumulate ---
    // df(d) = (d+0.5)*(48/193) - 0.5 = (96d - 145)/386  (exact integer form)
    float sum0 = 0.f, sum1 = 0.f, dsum0 = 0.f, dsum1 = 0.f;
    #pragma unroll
    for (int d = 0; d < D_OUT; ++d) {
        int num = 96 * d - 145;
        int k0 = (num >= 0) ? (num / 386) : -1;
        float fd = (float)(num - 386 * k0) * (1.0f / 386.0f);
        if (k0 < 0) { k0 = 0; fd = 0.f; }
        if (k0 >= D_IN - 1) { k0 = D_IN - 1; fd = 0.f; }
        int k1 = (k0 + 1 < D_IN) ? k0 + 1 : D_IN - 1;
        float arg = fmaf(fd, c[k1] - c[k0], c[k0]);   // delta CSE'd per segment
        float e;
        asm("v_exp_f32 %0, %1" : "=v"(e) : "v"(arg)); // native exp2, 1 instr
        if (d & 1) {
            sum1 += e;
            dsum1 = fmaf((float)d, e, dsum1);
        } else {
            sum0 += e;
            dsum0 = fmaf((float)d, e, dsum0);
        }
    }

    out[tid] = (dsum0 + dsum1) / (sum0 + sum1);
}

extern "C" void kernel_launch(void* const* d_in, const int* in_sizes, int n_in,
                              void* d_out, int out_size, void* d_ws, size_t ws_size,
                              hipStream_t stream) {
    const float* x = (const float*)d_in[0];
    float* out = (float*)d_out;
    int total = 2 * H_OUT * W_OUT;           // 262144
    disp_kernel<<<total / 256, 256, 0, stream>>>(x, out);
}

// Round 3
// 18.960 us; speedup vs baseline: 1.2210x; 1.0742x over previous
//
#include <hip/hip_runtime.h>

#define D_IN  48
#define H_IN  64
#define W_IN  128
#define D_OUT 193
#define H_OUT 256
#define W_OUT 512
#define NCOL  66    // staged columns per row: 64 distinct w0 + 1 neighbor + 1 slack

// One thread per output pixel (b,h,w). A 256-thread block covers 256
// consecutive w at fixed (b,h) -> all threads share input rows h0,h0+1 and a
// 66-column window. Stage [48][2][66] floats (25 KB) into LDS cooperatively
// (coalesced), then bilinear-interp from LDS via one VGPR base + compile-time
// immediate-offset ds_read_b32 (192 reads, conflict-free: lanes hit ~17
// consecutive dwords, 4-lane broadcast per address).
//
// Softmax: g[k] = (cmin - c[k])*log2e precomputed in place (lerp commutes
// with affine maps); per d: arg = fma(fd, g[k1]-g[k0], g[k0]), e = exp2(arg)
// via native v_exp_f32. Border clamps expressed as (pair base, adjusted
// fraction) so all reads are in-range pairs.
__global__ __launch_bounds__(256) void disp_kernel(const float* __restrict__ x,
                                                   float* __restrict__ out) {
    __shared__ float sm[D_IN * 2 * NCOL];   // 25344 B

    int t = threadIdx.x;
    int tid0 = blockIdx.x << 8;
    int tid = tid0 + t;
    int w = tid & (W_OUT - 1);
    int h = (tid >> 9) & (H_OUT - 1);
    int b = tid >> 17;                      // block-uniform
    int wblk = tid0 & (W_OUT - 1);          // block's starting w (multiple of 256)

    // --- h interpolation (block-uniform; half-pixel, clamp via pair+frac) ---
    float hf = (h + 0.5f) * 0.25f - 0.5f;
    float hfl = floorf(hf);
    int h0 = (int)hfl;
    float fh = hf - hfl;
    int hp; float fhp;
    if (h0 < 0)              { hp = 0;        fhp = 0.f; }
    else if (h0 >= H_IN - 1) { hp = H_IN - 2; fhp = 1.f; }
    else                     { hp = h0;       fhp = fh;  }

    // --- w interpolation ---
    float wf = (w + 0.5f) * 0.25f - 0.5f;
    float wfl = floorf(wf);
    int w0 = (int)wfl;
    float fw = wf - wfl;
    int wp; float fwp;
    if (w0 < 0)              { wp = 0;        fwp = 0.f; }
    else if (w0 >= W_IN - 1) { wp = W_IN - 2; fwp = 1.f; }
    else                     { wp = w0;       fwp = fw;  }

    // --- cooperative staging: sm[k][r][j] = x[b][k][hp+r][min(col0+j,127)] ---
    int col0 = (wblk >> 2) - 1; if (col0 < 0) col0 = 0;
    const float* xb = x + (size_t)b * (D_IN * H_IN * W_IN) + hp * W_IN;
    for (int i = t; i < D_IN * 2 * NCOL; i += 256) {
        int k   = i / (2 * NCOL);
        int rem = i - k * (2 * NCOL);
        int r   = rem / NCOL;
        int j   = rem - r * NCOL;
        int col = col0 + j; if (col > W_IN - 1) col = W_IN - 1;
        sm[i] = xb[k * (H_IN * W_IN) + r * W_IN + col];
    }
    __syncthreads();

    float w00 = (1.f - fhp) * (1.f - fwp);
    float w01 = (1.f - fhp) * fwp;
    float w10 = fhp * (1.f - fwp);
    float w11 = fhp * fwp;

    // --- bilinear column c[k] from LDS; track min ---
    const float* base = &sm[wp - col0];     // single VGPR base; k offsets are imms
    float c[D_IN];
    float cmin = 1e30f;
    #pragma unroll
    for (int k = 0; k < D_IN; ++k) {
        float a0 = base[(2 * k    ) * NCOL    ];
        float a1 = base[(2 * k    ) * NCOL + 1];
        float b0 = base[(2 * k + 1) * NCOL    ];
        float b1 = base[(2 * k + 1) * NCOL + 1];
        float v = w00 * a0 + w01 * a1 + w10 * b0 + w11 * b1;
        c[k] = v;
        cmin = fminf(cmin, v);
    }

    // --- transform in place: g[k] = (cmin - c[k]) * log2e  (<= 0) ---
    const float L2E = 1.4426950408889634f;
    float gbase = cmin * L2E;
    #pragma unroll
    for (int k = 0; k < D_IN; ++k) {
        c[k] = fmaf(c[k], -L2E, gbase);
    }

    // --- d loop: arg = lerp(g[k0], g[k1], fd); e = 2^arg; accumulate ---
    // df(d) = (d+0.5)*(48/193) - 0.5 = (96d - 145)/386  (exact integer form)
    float sum0 = 0.f, sum1 = 0.f, sum2 = 0.f, sum3 = 0.f;
    float dsum0 = 0.f, dsum1 = 0.f, dsum2 = 0.f, dsum3 = 0.f;
    #pragma unroll
    for (int d = 0; d < D_OUT; ++d) {
        int num = 96 * d - 145;
        int k0 = (num >= 0) ? (num / 386) : -1;
        float fd = (float)(num - 386 * k0) * (1.0f / 386.0f);
        if (k0 < 0) { k0 = 0; fd = 0.f; }
        if (k0 >= D_IN - 1) { k0 = D_IN - 1; fd = 0.f; }
        int k1 = (k0 + 1 < D_IN) ? k0 + 1 : D_IN - 1;
        float arg = fmaf(fd, c[k1] - c[k0], c[k0]);   // delta CSE'd per segment
        float e;
        asm("v_exp_f32 %0, %1" : "=v"(e) : "v"(arg)); // native exp2, 1 instr
        switch (d & 3) {
            case 0: sum0 += e; dsum0 = fmaf((float)d, e, dsum0); break;
            case 1: sum1 += e; dsum1 = fmaf((float)d, e, dsum1); break;
            case 2: sum2 += e; dsum2 = fmaf((float)d, e, dsum2); break;
            default: sum3 += e; dsum3 = fmaf((float)d, e, dsum3); break;
        }
    }

    out[tid] = ((dsum0 + dsum1) + (dsum2 + dsum3)) /
               ((sum0 + sum1) + (sum2 + sum3));
}

extern "C" void kernel_launch(void* const* d_in, const int* in_sizes, int n_in,
                              void* d_out, int out_size, void* d_ws, size_t ws_size,
                              hipStream_t stream) {
    const float* x = (const float*)d_in[0];
    float* out = (float*)d_out;
    int total = 2 * H_OUT * W_OUT;           // 262144
    disp_kernel<<<total / 256, 256, 0, stream>>>(x, out);
}